// Round 1
// baseline (311.943 us; speedup 1.0000x reference)
//
#include <hip/hip_runtime.h>
#include <hip/hip_bf16.h>

// ---------------- problem constants ----------------
constexpr int E_ = 16, K_ = 2, D_ = 1024, F_ = 512, T_ = 4096;
constexpr int TK_ = T_ * K_;          // 8192 (token,expert) slots
constexpr int CAP_ = 2048;            // per-expert capacity
constexpr int BM_ = 128;              // row-tile alignment
constexpr int ROWS_MAX = 10240;       // TK + E*(BM-1) rounded up

// ---------------- workspace layout (bytes) ----------------
constexpr size_t SZ_W   = (size_t)E_ * F_ * D_ * 2;      // one bf16 weight matrix set
constexpr size_t OFF_WGT  = 0;
constexpr size_t OFF_WUT  = OFF_WGT + SZ_W;
constexpr size_t OFF_WDT  = OFF_WUT + SZ_W;
constexpr size_t OFF_XG   = OFF_WDT + SZ_W;
constexpr size_t SZ_XG  = (size_t)ROWS_MAX * D_ * 2;
constexpr size_t OFF_H    = OFF_XG + SZ_XG;
constexpr size_t SZ_H   = (size_t)ROWS_MAX * F_ * 2;
constexpr size_t OFF_Y    = OFF_H + SZ_H;
constexpr size_t SZ_Y   = (size_t)ROWS_MAX * D_ * 4;
constexpr size_t OFF_META = OFF_Y + SZ_Y;
// meta ints: [0:16) cnt_raw, [16:32) cnt2, [32:48) cnt_c, [48:64) off_al,
//            [64:64+TK) pair_row, [64+TK : 64+TK+ROWS_MAX) row_token

typedef __attribute__((ext_vector_type(8))) short short8;
typedef __attribute__((ext_vector_type(4))) float float4v;

__device__ __forceinline__ unsigned short f2bf(float f) {
  union { float f; unsigned int u; } v; v.f = f;
  unsigned int r = (v.u + 0x7fffu + ((v.u >> 16) & 1u)) >> 16;
  return (unsigned short)r;
}

__device__ __forceinline__ void load_lds16(const unsigned short* g, unsigned short* l) {
  __builtin_amdgcn_global_load_lds(
      (const __attribute__((address_space(1))) unsigned int*)g,
      (__attribute__((address_space(3))) unsigned int*)l,
      16, 0, 0);
}

// ---------------- dispatch ----------------
__global__ void hist_k(const int* __restrict__ idx, int* __restrict__ cnt_raw) {
  int i = blockIdx.x * 256 + threadIdx.x;   // grid covers TK
  atomicAdd(&cnt_raw[idx[i]], 1);
}

__global__ void offsets_k(const int* __restrict__ cnt_raw, int* __restrict__ cnt_c,
                          int* __restrict__ off_al) {
  if (threadIdx.x == 0 && blockIdx.x == 0) {
    int run = 0;
    for (int e = 0; e < E_; ++e) {
      int c = cnt_raw[e]; if (c > CAP_) c = CAP_;
      cnt_c[e] = c;
      off_al[e] = run;
      run += (c + BM_ - 1) & ~(BM_ - 1);
    }
  }
}

__global__ void assign_k(const int* __restrict__ idx, int* __restrict__ cnt2,
                         const int* __restrict__ off_al, int* __restrict__ pair_row,
                         int* __restrict__ row_token) {
  int i = blockIdx.x * 256 + threadIdx.x;   // 0..TK-1
  int e = idx[i];
  int r = atomicAdd(&cnt2[e], 1);
  if (r < CAP_) {
    int row = off_al[e] + r;
    pair_row[i] = row;
    row_token[row] = i >> 1;                // source token
  } else {
    pair_row[i] = -1;
  }
}

// ---------------- gather tokens -> bf16 grouped rows ----------------
__global__ void gather_k(const float* __restrict__ hidden, const int* __restrict__ row_token,
                         unsigned short* __restrict__ Xg) {
  int r = blockIdx.x;                 // 0..ROWS_MAX-1
  int tok = row_token[r];
  int c = threadIdx.x * 4;            // 256 thr * 4 = D
  ushort4 o;
  if (tok >= 0) {
    float4 v = *(const float4*)(hidden + (size_t)tok * D_ + c);
    o.x = f2bf(v.x); o.y = f2bf(v.y); o.z = f2bf(v.z); o.w = f2bf(v.w);
  } else {
    o.x = 0; o.y = 0; o.z = 0; o.w = 0;
  }
  *(ushort4*)(Xg + (size_t)r * D_ + c) = o;
}

// ---------------- transpose-cast weights: per-expert [R][C] f32 -> [C][R] bf16 ----------------
__global__ void transpose_cast_k(const float* __restrict__ src, unsigned short* __restrict__ dst,
                                 int R, int C) {
  __shared__ float tile[32][33];
  int e = blockIdx.z;
  const float* s = src + (size_t)e * R * C;
  unsigned short* d = dst + (size_t)e * R * C;
  int c0 = blockIdx.x * 32, r0 = blockIdx.y * 32;
  int tr = threadIdx.x >> 3;          // 0..31
  int tc = (threadIdx.x & 7) * 4;     // 0,4,..,28
  float4 v = *(const float4*)(s + (size_t)(r0 + tr) * C + (c0 + tc));
  tile[tr][tc + 0] = v.x; tile[tr][tc + 1] = v.y;
  tile[tr][tc + 2] = v.z; tile[tr][tc + 3] = v.w;
  __syncthreads();
  ushort4 o;
  o.x = f2bf(tile[tc + 0][tr]);
  o.y = f2bf(tile[tc + 1][tr]);
  o.z = f2bf(tile[tc + 2][tr]);
  o.w = f2bf(tile[tc + 3][tr]);
  *(ushort4*)(d + (size_t)(c0 + tr) * R + (r0 + tc)) = o;
}

// ---------------- GEMM1: H = silu(Xg @ Wg) * (Xg @ Wu), fused, bf16 out ----------------
// block tile 128(M) x 64(N), BK=64, 4 waves (2x2), wave tile 64x32 per matrix
__launch_bounds__(256)
__global__ void gemm1_k(const unsigned short* __restrict__ Xg,
                        const unsigned short* __restrict__ WgT,
                        const unsigned short* __restrict__ WuT,
                        unsigned short* __restrict__ Hbuf,
                        const int* __restrict__ cnt_c, const int* __restrict__ off_al) {
  int e = blockIdx.z, mt = blockIdx.y, nt = blockIdx.x;
  int cnt = cnt_c[e];
  if (mt * 128 >= cnt) return;
  int rbase = off_al[e] + mt * 128;

  __shared__ unsigned short lA[128 * 64];
  __shared__ unsigned short lBg[64 * 64];
  __shared__ unsigned short lBu[64 * 64];

  int tid = threadIdx.x, wid = tid >> 6, lane = tid & 63;
  int wm = wid >> 1, wn = wid & 1;
  int quad = lane >> 4, l15 = lane & 15;

  const unsigned short* gA = Xg + (size_t)rbase * D_;
  const unsigned short* gB0 = WgT + ((size_t)e * F_ + nt * 64) * D_;
  const unsigned short* gB1 = WuT + ((size_t)e * F_ + nt * 64) * D_;

  float4v accg[4][2], accu[4][2];
#pragma unroll
  for (int i = 0; i < 4; ++i)
#pragma unroll
    for (int j = 0; j < 2; ++j) {
      accg[i][j] = (float4v){0.f, 0.f, 0.f, 0.f};
      accu[i][j] = (float4v){0.f, 0.f, 0.f, 0.f};
    }

  for (int k0 = 0; k0 < D_; k0 += 64) {
    __syncthreads();
#pragma unroll
    for (int it = 0; it < 4; ++it) {          // A tile: 128x64 bf16 = 16KB
      int fw = it * 256 + wid * 64;
      int f = fw + lane;
      load_lds16(gA + ((size_t)(f >> 3)) * D_ + k0 + (f & 7) * 8, &lA[(size_t)fw * 8]);
    }
#pragma unroll
    for (int it = 0; it < 2; ++it) {          // each B tile: 64x64 bf16 = 8KB
      int fw = it * 256 + wid * 64;
      int f = fw + lane;
      size_t go = ((size_t)(f >> 3)) * D_ + k0 + (f & 7) * 8;
      load_lds16(gB0 + go, &lBg[(size_t)fw * 8]);
      load_lds16(gB1 + go, &lBu[(size_t)fw * 8]);
    }
    __syncthreads();
#pragma unroll
    for (int kc = 0; kc < 2; ++kc) {
      short8 af[4], bg[2], bu[2];
#pragma unroll
      for (int i = 0; i < 4; ++i)
        af[i] = *(const short8*)&lA[(wm * 64 + i * 16 + l15) * 64 + kc * 32 + quad * 8];
#pragma unroll
      for (int j = 0; j < 2; ++j) {
        int n = wn * 32 + j * 16 + l15;
        bg[j] = *(const short8*)&lBg[n * 64 + kc * 32 + quad * 8];
        bu[j] = *(const short8*)&lBu[n * 64 + kc * 32 + quad * 8];
      }
#pragma unroll
      for (int i = 0; i < 4; ++i)
#pragma unroll
        for (int j = 0; j < 2; ++j) {
          accg[i][j] = __builtin_amdgcn_mfma_f32_16x16x32_bf16(af[i], bg[j], accg[i][j], 0, 0, 0);
          accu[i][j] = __builtin_amdgcn_mfma_f32_16x16x32_bf16(af[i], bu[j], accu[i][j], 0, 0, 0);
        }
    }
  }

  int rem = cnt - mt * 128;
#pragma unroll
  for (int i = 0; i < 4; ++i)
#pragma unroll
    for (int j = 0; j < 2; ++j)
#pragma unroll
      for (int r = 0; r < 4; ++r) {
        int row = wm * 64 + i * 16 + quad * 4 + r;
        if (row < rem) {
          float g = accg[i][j][r], u = accu[i][j][r];
          float h = (g / (1.f + __expf(-g))) * u;   // silu(g)*u
          int n = nt * 64 + wn * 32 + j * 16 + l15;
          Hbuf[(size_t)(rbase + row) * F_ + n] = f2bf(h);
        }
      }
}

// ---------------- GEMM2: Y = H @ WdT^T, fp32 out ----------------
// block tile 128x128, BK=64, 4 waves (2x2), wave tile 64x64
__launch_bounds__(256)
__global__ void gemm2_k(const unsigned short* __restrict__ Hbuf,
                        const unsigned short* __restrict__ WdT,
                        float* __restrict__ Y,
                        const int* __restrict__ cnt_c, const int* __restrict__ off_al) {
  int e = blockIdx.z, mt = blockIdx.y, nt = blockIdx.x;
  int cnt = cnt_c[e];
  if (mt * 128 >= cnt) return;
  int rbase = off_al[e] + mt * 128;

  __shared__ unsigned short lA[128 * 64];
  __shared__ unsigned short lB[128 * 64];

  int tid = threadIdx.x, wid = tid >> 6, lane = tid & 63;
  int wm = wid >> 1, wn = wid & 1;
  int quad = lane >> 4, l15 = lane & 15;

  const unsigned short* gA = Hbuf + (size_t)rbase * F_;
  const unsigned short* gB = WdT + ((size_t)e * D_ + nt * 128) * F_;

  float4v acc[4][4];
#pragma unroll
  for (int i = 0; i < 4; ++i)
#pragma unroll
    for (int j = 0; j < 4; ++j) acc[i][j] = (float4v){0.f, 0.f, 0.f, 0.f};

  for (int k0 = 0; k0 < F_; k0 += 64) {
    __syncthreads();
#pragma unroll
    for (int it = 0; it < 4; ++it) {
      int fw = it * 256 + wid * 64;
      int f = fw + lane;
      size_t go = ((size_t)(f >> 3)) * F_ + k0 + (f & 7) * 8;
      load_lds16(gA + go, &lA[(size_t)fw * 8]);
      load_lds16(gB + go, &lB[(size_t)fw * 8]);
    }
    __syncthreads();
#pragma unroll
    for (int kc = 0; kc < 2; ++kc) {
      short8 af[4], bf[4];
#pragma unroll
      for (int i = 0; i < 4; ++i)
        af[i] = *(const short8*)&lA[(wm * 64 + i * 16 + l15) * 64 + kc * 32 + quad * 8];
#pragma unroll
      for (int j = 0; j < 4; ++j)
        bf[j] = *(const short8*)&lB[(wn * 64 + j * 16 + l15) * 64 + kc * 32 + quad * 8];
#pragma unroll
      for (int i = 0; i < 4; ++i)
#pragma unroll
        for (int j = 0; j < 4; ++j)
          acc[i][j] = __builtin_amdgcn_mfma_f32_16x16x32_bf16(af[i], bf[j], acc[i][j], 0, 0, 0);
    }
  }

  int rem = cnt - mt * 128;
#pragma unroll
  for (int i = 0; i < 4; ++i)
#pragma unroll
    for (int j = 0; j < 4; ++j)
#pragma unroll
      for (int r = 0; r < 4; ++r) {
        int row = wm * 64 + i * 16 + quad * 4 + r;
        if (row < rem) {
          int n = nt * 128 + wn * 64 + j * 16 + l15;
          Y[(size_t)(rbase + row) * D_ + n] = acc[i][j][r];
        }
      }
}

// ---------------- combine: out[t] = sum_k w * Y[row(t,k)] ----------------
__global__ void combine_k(const float* __restrict__ Y, const int* __restrict__ pair_row,
                          const float* __restrict__ tw, float* __restrict__ out) {
  int t = blockIdx.x;
  int c = threadIdx.x * 4;
  int r0 = pair_row[2 * t], r1 = pair_row[2 * t + 1];
  float w0 = tw[2 * t], w1 = tw[2 * t + 1];
  float4 a = {0.f, 0.f, 0.f, 0.f};
  if (r0 >= 0) {
    float4 v = *(const float4*)(Y + (size_t)r0 * D_ + c);
    a.x += w0 * v.x; a.y += w0 * v.y; a.z += w0 * v.z; a.w += w0 * v.w;
  }
  if (r1 >= 0) {
    float4 v = *(const float4*)(Y + (size_t)r1 * D_ + c);
    a.x += w1 * v.x; a.y += w1 * v.y; a.z += w1 * v.z; a.w += w1 * v.w;
  }
  *(float4*)(out + (size_t)t * D_ + c) = a;
}

// ---------------- launch ----------------
extern "C" void kernel_launch(void* const* d_in, const int* in_sizes, int n_in,
                              void* d_out, int out_size, void* d_ws, size_t ws_size,
                              hipStream_t stream) {
  const float* hidden  = (const float*)d_in[0];
  const int*   topkidx = (const int*)d_in[1];
  const float* topkw   = (const float*)d_in[2];
  const float* w_gate  = (const float*)d_in[3];
  const float* w_up    = (const float*)d_in[4];
  const float* w_down  = (const float*)d_in[5];
  float* out = (float*)d_out;

  char* ws = (char*)d_ws;
  unsigned short* WgT = (unsigned short*)(ws + OFF_WGT);
  unsigned short* WuT = (unsigned short*)(ws + OFF_WUT);
  unsigned short* WdT = (unsigned short*)(ws + OFF_WDT);
  unsigned short* Xg  = (unsigned short*)(ws + OFF_XG);
  unsigned short* Hb  = (unsigned short*)(ws + OFF_H);
  float* Y            = (float*)(ws + OFF_Y);
  int* meta           = (int*)(ws + OFF_META);
  int* cnt_raw  = meta;
  int* cnt2     = meta + 16;
  int* cnt_c    = meta + 32;
  int* off_al   = meta + 48;
  int* pair_row = meta + 64;
  int* row_token = meta + 64 + TK_;

  // zero counters; row_token = -1 everywhere (0xFF bytes)
  hipMemsetAsync(meta, 0, 64 * sizeof(int), stream);
  hipMemsetAsync(row_token, 0xFF, (size_t)ROWS_MAX * sizeof(int), stream);

  hist_k<<<TK_ / 256, 256, 0, stream>>>(topkidx, cnt_raw);
  offsets_k<<<1, 64, 0, stream>>>(cnt_raw, cnt_c, off_al);
  assign_k<<<TK_ / 256, 256, 0, stream>>>(topkidx, cnt2, off_al, pair_row, row_token);

  // weight transpose-casts (independent of dispatch)
  transpose_cast_k<<<dim3(F_ / 32, D_ / 32, E_), 256, 0, stream>>>(w_gate, WgT, D_, F_);
  transpose_cast_k<<<dim3(F_ / 32, D_ / 32, E_), 256, 0, stream>>>(w_up,   WuT, D_, F_);
  transpose_cast_k<<<dim3(D_ / 32, F_ / 32, E_), 256, 0, stream>>>(w_down, WdT, F_, D_);

  gather_k<<<ROWS_MAX, 256, 0, stream>>>(hidden, row_token, Xg);

  gemm1_k<<<dim3(F_ / 64, 16, E_), 256, 0, stream>>>(Xg, WgT, WuT, Hb, cnt_c, off_al);
  gemm2_k<<<dim3(D_ / 128, 16, E_), 256, 0, stream>>>(Hb, WdT, Y, cnt_c, off_al);

  combine_k<<<T_, 256, 0, stream>>>(Y, pair_row, topkw, out);
}

// Round 2
// 269.914 us; speedup vs baseline: 1.1557x; 1.1557x over previous
//
#include <hip/hip_runtime.h>
#include <hip/hip_bf16.h>

// ---------------- problem constants ----------------
constexpr int E_ = 16, K_ = 2, D_ = 1024, F_ = 512, T_ = 4096;
constexpr int TK_ = T_ * K_;          // 8192 (token,expert) slots
constexpr int CAP_ = 2048;            // per-expert capacity
constexpr int BM_ = 128;              // row-tile alignment
constexpr int ROWS_MAX = 10240;       // TK + E*(BM-1) rounded up

// ---------------- workspace layout (bytes) ----------------
constexpr size_t SZ_W   = (size_t)E_ * F_ * D_ * 2;      // one bf16 weight matrix
constexpr size_t OFF_WGT  = 0;
constexpr size_t OFF_WUT  = OFF_WGT + SZ_W;
constexpr size_t OFF_WDT  = OFF_WUT + SZ_W;
constexpr size_t OFF_XG   = OFF_WDT + SZ_W;
constexpr size_t SZ_XG  = (size_t)ROWS_MAX * D_ * 2;
constexpr size_t OFF_H    = OFF_XG + SZ_XG;
constexpr size_t SZ_H   = (size_t)ROWS_MAX * F_ * 2;
constexpr size_t OFF_META = OFF_H + SZ_H;
// meta: cnt_c[16], off_al[16], row_token[ROWS_MAX] (int), row_weight[ROWS_MAX] (float)

typedef __attribute__((ext_vector_type(8))) short short8;
typedef __attribute__((ext_vector_type(4))) float float4v;

__device__ __forceinline__ unsigned short f2bf(float f) {
  union { float f; unsigned int u; } v; v.f = f;
  unsigned int r = (v.u + 0x7fffu + ((v.u >> 16) & 1u)) >> 16;
  return (unsigned short)r;
}

__device__ __forceinline__ void load_lds16(const unsigned short* g, unsigned short* l) {
  __builtin_amdgcn_global_load_lds(
      (const __attribute__((address_space(1))) unsigned int*)g,
      (__attribute__((address_space(3))) unsigned int*)l,
      16, 0, 0);
}

// ---------------- dispatch: hist + offsets + rank-assign in ONE block ----------------
__launch_bounds__(1024)
__global__ void dispatch_k(const int* __restrict__ idx, const float* __restrict__ tw,
                           int* __restrict__ cnt_c, int* __restrict__ off_al,
                           int* __restrict__ row_token, float* __restrict__ row_weight) {
  __shared__ int hist[E_], offs[E_], ctr[E_];
  int tid = threadIdx.x;
  if (tid < E_) hist[tid] = 0;
  __syncthreads();
  for (int i = tid; i < TK_; i += 1024) atomicAdd(&hist[idx[i]], 1);
  __syncthreads();
  if (tid == 0) {
    int run = 0;
    for (int e = 0; e < E_; ++e) {
      int c = hist[e] > CAP_ ? CAP_ : hist[e];
      cnt_c[e] = c; off_al[e] = run; offs[e] = run; ctr[e] = 0;
      run += (c + BM_ - 1) & ~(BM_ - 1);
    }
  }
  __syncthreads();
  for (int r = tid; r < ROWS_MAX; r += 1024) row_token[r] = -1;
  __syncthreads();
  for (int i = tid; i < TK_; i += 1024) {
    int e = idx[i];
    int r = atomicAdd(&ctr[e], 1);
    if (r < CAP_) {
      int row = offs[e] + r;
      row_token[row] = i >> 1;              // source token
      row_weight[row] = tw[i];
    }
  }
}

// ---------------- gather tokens -> bf16 grouped rows ----------------
__global__ void gather_k(const float* __restrict__ hidden, const int* __restrict__ row_token,
                         unsigned short* __restrict__ Xg) {
  int r = blockIdx.x;                 // 0..ROWS_MAX-1
  int tok = row_token[r];
  int c = threadIdx.x * 4;            // 256 thr * 4 = D
  ushort4 o;
  if (tok >= 0) {
    float4 v = *(const float4*)(hidden + (size_t)tok * D_ + c);
    o.x = f2bf(v.x); o.y = f2bf(v.y); o.z = f2bf(v.z); o.w = f2bf(v.w);
  } else {
    o.x = 0; o.y = 0; o.z = 0; o.w = 0;
  }
  *(ushort4*)(Xg + (size_t)r * D_ + c) = o;
}

// ---------------- transpose-cast all three weight tensors in one launch ----------------
// per-expert [R][C] f32 -> [C][R] bf16
__global__ void transpose_all_k(const float* __restrict__ wg, const float* __restrict__ wu,
                                const float* __restrict__ wd,
                                unsigned short* __restrict__ WgT, unsigned short* __restrict__ WuT,
                                unsigned short* __restrict__ WdT) {
  __shared__ float tile[32][33];
  int z = blockIdx.y;                 // 0..47
  int kind = z >> 4, e = z & 15;
  int R = (kind == 2) ? F_ : D_;
  int C = (kind == 2) ? D_ : F_;
  const float* s = ((kind == 0) ? wg : (kind == 1) ? wu : wd) + (size_t)e * R * C;
  unsigned short* d = ((kind == 0) ? WgT : (kind == 1) ? WuT : WdT) + (size_t)e * R * C;
  int tilesX = C >> 5;
  int t = blockIdx.x;                 // 0..511 (R/32 * C/32 == 512 for both shapes)
  int r0 = (t / tilesX) * 32, c0 = (t % tilesX) * 32;
  int tr = threadIdx.x >> 3;          // 0..31
  int tc = (threadIdx.x & 7) * 4;     // 0,4,..,28
  float4 v = *(const float4*)(s + (size_t)(r0 + tr) * C + (c0 + tc));
  tile[tr][tc + 0] = v.x; tile[tr][tc + 1] = v.y;
  tile[tr][tc + 2] = v.z; tile[tr][tc + 3] = v.w;
  __syncthreads();
  ushort4 o;
  o.x = f2bf(tile[tc + 0][tr]);
  o.y = f2bf(tile[tc + 1][tr]);
  o.z = f2bf(tile[tc + 2][tr]);
  o.w = f2bf(tile[tc + 3][tr]);
  *(ushort4*)(d + (size_t)(c0 + tr) * R + (r0 + tc)) = o;
}

// ---- swizzled staging: store global col-chunk (sl ^ (row&7)) at LDS slot sl ----
// LDS[row][sl] then holds col8 = sl ^ (row&7); read col8 c at slot c ^ (row&7).
// Breaks the 16-way bank conflict of the naive row-major layout (row stride = 32 banks).

// ---------------- GEMM1: H = silu(Xg @ Wg) * (Xg @ Wu), fused, bf16 out ----------------
// block tile 128(M) x 64(N), BK=64, 4 waves (2x2)
__launch_bounds__(256)
__global__ void gemm1_k(const unsigned short* __restrict__ Xg,
                        const unsigned short* __restrict__ WgT,
                        const unsigned short* __restrict__ WuT,
                        unsigned short* __restrict__ Hbuf,
                        const int* __restrict__ cnt_c, const int* __restrict__ off_al) {
  int e = blockIdx.z, mt = blockIdx.y, nt = blockIdx.x;
  int cnt = cnt_c[e];
  if (mt * 128 >= cnt) return;
  int rbase = off_al[e] + mt * 128;

  __shared__ unsigned short lA[128 * 64];
  __shared__ unsigned short lBg[64 * 64];
  __shared__ unsigned short lBu[64 * 64];

  int tid = threadIdx.x, wid = tid >> 6, lane = tid & 63;
  int wm = wid >> 1, wn = wid & 1;
  int quad = lane >> 4, l15 = lane & 15;
  int sw = l15 & 7;                   // row&7 for all fragment rows below

  const unsigned short* gA = Xg + (size_t)rbase * D_;
  const unsigned short* gB0 = WgT + ((size_t)e * F_ + nt * 64) * D_;
  const unsigned short* gB1 = WuT + ((size_t)e * F_ + nt * 64) * D_;

  float4v accg[4][2], accu[4][2];
#pragma unroll
  for (int i = 0; i < 4; ++i)
#pragma unroll
    for (int j = 0; j < 2; ++j) {
      accg[i][j] = (float4v){0.f, 0.f, 0.f, 0.f};
      accu[i][j] = (float4v){0.f, 0.f, 0.f, 0.f};
    }

  for (int k0 = 0; k0 < D_; k0 += 64) {
    __syncthreads();
#pragma unroll
    for (int it = 0; it < 4; ++it) {          // A tile: 128x64 bf16 = 16KB
      int fw = it * 256 + wid * 64;
      int f = fw + lane;
      int row = f >> 3, c8 = (f & 7) ^ (row & 7);
      load_lds16(gA + (size_t)row * D_ + k0 + c8 * 8, &lA[(size_t)fw * 8]);
    }
#pragma unroll
    for (int it = 0; it < 2; ++it) {          // each B tile: 64x64 bf16 = 8KB
      int fw = it * 256 + wid * 64;
      int f = fw + lane;
      int row = f >> 3, c8 = (f & 7) ^ (row & 7);
      size_t go = (size_t)row * D_ + k0 + c8 * 8;
      load_lds16(gB0 + go, &lBg[(size_t)fw * 8]);
      load_lds16(gB1 + go, &lBu[(size_t)fw * 8]);
    }
    __syncthreads();
#pragma unroll
    for (int kc = 0; kc < 2; ++kc) {
      short8 af[4], bg[2], bu[2];
#pragma unroll
      for (int i = 0; i < 4; ++i) {
        int r = wm * 64 + i * 16 + l15;
        af[i] = *(const short8*)&lA[r * 64 + ((kc * 4 + quad) ^ sw) * 8];
      }
#pragma unroll
      for (int j = 0; j < 2; ++j) {
        int n = wn * 32 + j * 16 + l15;
        bg[j] = *(const short8*)&lBg[n * 64 + ((kc * 4 + quad) ^ sw) * 8];
        bu[j] = *(const short8*)&lBu[n * 64 + ((kc * 4 + quad) ^ sw) * 8];
      }
#pragma unroll
      for (int i = 0; i < 4; ++i)
#pragma unroll
        for (int j = 0; j < 2; ++j) {
          accg[i][j] = __builtin_amdgcn_mfma_f32_16x16x32_bf16(af[i], bg[j], accg[i][j], 0, 0, 0);
          accu[i][j] = __builtin_amdgcn_mfma_f32_16x16x32_bf16(af[i], bu[j], accu[i][j], 0, 0, 0);
        }
    }
  }

  int rem = cnt - mt * 128;
#pragma unroll
  for (int i = 0; i < 4; ++i)
#pragma unroll
    for (int j = 0; j < 2; ++j)
#pragma unroll
      for (int r = 0; r < 4; ++r) {
        int row = wm * 64 + i * 16 + quad * 4 + r;
        if (row < rem) {
          float g = accg[i][j][r], u = accu[i][j][r];
          float h = (g / (1.f + __expf(-g))) * u;   // silu(g)*u
          int n = nt * 64 + wn * 32 + j * 16 + l15;
          Hbuf[(size_t)(rbase + row) * F_ + n] = f2bf(h);
        }
      }
}

// ---------------- GEMM2 + fused weighted scatter: out[tok] += w * (H @ WdT^T) ----------------
// block tile 128x128, BK=64, 4 waves (2x2)
__launch_bounds__(256)
__global__ void gemm2_k(const unsigned short* __restrict__ Hbuf,
                        const unsigned short* __restrict__ WdT,
                        float* __restrict__ out,
                        const int* __restrict__ cnt_c, const int* __restrict__ off_al,
                        const int* __restrict__ row_token, const float* __restrict__ row_weight) {
  int e = blockIdx.z, mt = blockIdx.y, nt = blockIdx.x;
  int cnt = cnt_c[e];
  if (mt * 128 >= cnt) return;
  int rbase = off_al[e] + mt * 128;

  __shared__ unsigned short lA[128 * 64];
  __shared__ unsigned short lB[128 * 64];

  int tid = threadIdx.x, wid = tid >> 6, lane = tid & 63;
  int wm = wid >> 1, wn = wid & 1;
  int quad = lane >> 4, l15 = lane & 15;
  int sw = l15 & 7;

  const unsigned short* gA = Hbuf + (size_t)rbase * F_;
  const unsigned short* gB = WdT + ((size_t)e * D_ + nt * 128) * F_;

  float4v acc[4][4];
#pragma unroll
  for (int i = 0; i < 4; ++i)
#pragma unroll
    for (int j = 0; j < 4; ++j) acc[i][j] = (float4v){0.f, 0.f, 0.f, 0.f};

  for (int k0 = 0; k0 < F_; k0 += 64) {
    __syncthreads();
#pragma unroll
    for (int it = 0; it < 4; ++it) {
      int fw = it * 256 + wid * 64;
      int f = fw + lane;
      int row = f >> 3, c8 = (f & 7) ^ (row & 7);
      size_t go = (size_t)row * F_ + k0 + c8 * 8;
      load_lds16(gA + go, &lA[(size_t)fw * 8]);
      load_lds16(gB + go, &lB[(size_t)fw * 8]);
    }
    __syncthreads();
#pragma unroll
    for (int kc = 0; kc < 2; ++kc) {
      short8 af[4], bf[4];
#pragma unroll
      for (int i = 0; i < 4; ++i) {
        int r = wm * 64 + i * 16 + l15;
        af[i] = *(const short8*)&lA[r * 64 + ((kc * 4 + quad) ^ sw) * 8];
      }
#pragma unroll
      for (int j = 0; j < 4; ++j) {
        int n = wn * 64 + j * 16 + l15;
        bf[j] = *(const short8*)&lB[n * 64 + ((kc * 4 + quad) ^ sw) * 8];
      }
#pragma unroll
      for (int i = 0; i < 4; ++i)
#pragma unroll
        for (int j = 0; j < 4; ++j)
          acc[i][j] = __builtin_amdgcn_mfma_f32_16x16x32_bf16(af[i], bf[j], acc[i][j], 0, 0, 0);
    }
  }

  int rem = cnt - mt * 128;
#pragma unroll
  for (int i = 0; i < 4; ++i)
#pragma unroll
    for (int r = 0; r < 4; ++r) {
      int row = wm * 64 + i * 16 + quad * 4 + r;
      if (row < rem) {
        int gr = rbase + row;
        int tok = row_token[gr];
        if (tok >= 0) {
          float w = row_weight[gr];
          float* op = out + (size_t)tok * D_;
#pragma unroll
          for (int j = 0; j < 4; ++j) {
            int n = nt * 128 + wn * 64 + j * 16 + l15;
            atomicAdd(op + n, w * acc[i][j][r]);
          }
        }
      }
    }
}

// ---------------- launch ----------------
extern "C" void kernel_launch(void* const* d_in, const int* in_sizes, int n_in,
                              void* d_out, int out_size, void* d_ws, size_t ws_size,
                              hipStream_t stream) {
  const float* hidden  = (const float*)d_in[0];
  const int*   topkidx = (const int*)d_in[1];
  const float* topkw   = (const float*)d_in[2];
  const float* w_gate  = (const float*)d_in[3];
  const float* w_up    = (const float*)d_in[4];
  const float* w_down  = (const float*)d_in[5];
  float* out = (float*)d_out;

  char* ws = (char*)d_ws;
  unsigned short* WgT = (unsigned short*)(ws + OFF_WGT);
  unsigned short* WuT = (unsigned short*)(ws + OFF_WUT);
  unsigned short* WdT = (unsigned short*)(ws + OFF_WDT);
  unsigned short* Xg  = (unsigned short*)(ws + OFF_XG);
  unsigned short* Hb  = (unsigned short*)(ws + OFF_H);
  int* meta           = (int*)(ws + OFF_META);
  int* cnt_c    = meta;
  int* off_al   = meta + 16;
  int* row_token = meta + 32;
  float* row_weight = (float*)(meta + 32 + ROWS_MAX);

  // out must start at zero (scatter-add target); harness poisons it each call.
  hipMemsetAsync(out, 0, (size_t)out_size * sizeof(float), stream);

  dispatch_k<<<1, 1024, 0, stream>>>(topkidx, topkw, cnt_c, off_al, row_token, row_weight);
  transpose_all_k<<<dim3(512, 48), 256, 0, stream>>>(w_gate, w_up, w_down, WgT, WuT, WdT);
  gather_k<<<ROWS_MAX, 256, 0, stream>>>(hidden, row_token, Xg);

  gemm1_k<<<dim3(F_ / 64, CAP_ / 128, E_), 256, 0, stream>>>(Xg, WgT, WuT, Hb, cnt_c, off_al);
  gemm2_k<<<dim3(D_ / 128, CAP_ / 128, E_), 256, 0, stream>>>(Hb, WdT, out, cnt_c, off_al,
                                                              row_token, row_weight);
}